// Round 5
// baseline (3472.663 us; speedup 1.0000x reference)
//
#include <hip/hip_runtime.h>
#include <hip/hip_bf16.h>
#include <hip/hip_cooperative_groups.h>

namespace cg = cooperative_groups;

// Problem dims (fixed by reference)
#define B_  256
#define L_  64
#define DI_ 2048
#define T_  32
#define DT_ 512
#define U_  512
#define A_  512
#define N3U 1536   // 3*U

typedef short short8 __attribute__((ext_vector_type(8)));   // 8 bf16 = 4 VGPRs
typedef float floatx4 __attribute__((ext_vector_type(4)));  // mfma acc

// fp32 -> bf16 round-to-nearest-even
__device__ __forceinline__ unsigned short f2bf(float f) {
  unsigned int u = __float_as_uint(f);
  u += 0x7fffu + ((u >> 16) & 1u);
  return (unsigned short)(u >> 16);
}
__device__ __forceinline__ float bf2f(unsigned short s) {
  return __uint_as_float(((unsigned int)s) << 16);
}
__device__ __forceinline__ float fast_tanh(float x) {
  x = fminf(fmaxf(x, -15.f), 15.f);
  float e = __expf(2.f * x);
  return (e - 1.f) / (e + 1.f);
}
__device__ __forceinline__ float sigmoidf(float x) {
  return 1.f / (1.f + __expf(-x));
}

// ---------------------------------------------------------------------------
// MFMA GEMM with fused A-conversion (precompute only):
//   C[M,N] = A[M,K](fp32) @ Bt[N,K](bf16)^T (+bias), out fp32 or bf16.
// 128x128 tile, BK=32, 256 threads = 4 waves, each wave 64x64 sub-tile.
// ---------------------------------------------------------------------------
__global__ __launch_bounds__(256) void gemm_a32_bt16_mfma(
    const float* __restrict__ A, const unsigned short* __restrict__ Bt,
    const float* __restrict__ bias, void* __restrict__ Cout,
    int M, int N, int K, int out_bf16) {
  __shared__ unsigned short As[128][40];
  __shared__ unsigned short Bs[128][40];
  const int tid  = threadIdx.x;
  const int wave = tid >> 6;
  const int lane = tid & 63;
  const int quad = lane >> 4;
  const int lr   = lane & 15;
  const int wrow = (wave >> 1) * 64;
  const int wcol = (wave & 1) * 64;
  const size_t bm = (size_t)blockIdx.y * 128;
  const size_t bn = (size_t)blockIdx.x * 128;

  const int sr = tid >> 2;          // staging row 0..63
  const int sc = (tid & 3) * 8;     // staging col (ushorts) 0,8,16,24

  floatx4 acc[4][4] = {};

  for (int k0 = 0; k0 < K; k0 += 32) {
#pragma unroll
    for (int it = 0; it < 2; ++it) {
      const int row = sr + it * 64;
      const float* ap = A + (bm + row) * (size_t)K + k0 + sc;
      float4 a0 = *(const float4*)(ap);
      float4 a1 = *(const float4*)(ap + 4);
      short8 pk;
      pk[0] = (short)f2bf(a0.x); pk[1] = (short)f2bf(a0.y);
      pk[2] = (short)f2bf(a0.z); pk[3] = (short)f2bf(a0.w);
      pk[4] = (short)f2bf(a1.x); pk[5] = (short)f2bf(a1.y);
      pk[6] = (short)f2bf(a1.z); pk[7] = (short)f2bf(a1.w);
      *(short8*)&As[row][sc] = pk;
      *(float4*)&Bs[row][sc] = *(const float4*)(Bt + (bn + row) * (size_t)K + k0 + sc);
    }
    __syncthreads();
    short8 af[4], bf[4];
#pragma unroll
    for (int mi = 0; mi < 4; ++mi) af[mi] = *(const short8*)&As[wrow + mi * 16 + lr][quad * 8];
#pragma unroll
    for (int ni = 0; ni < 4; ++ni) bf[ni] = *(const short8*)&Bs[wcol + ni * 16 + lr][quad * 8];
#pragma unroll
    for (int mi = 0; mi < 4; ++mi)
#pragma unroll
      for (int ni = 0; ni < 4; ++ni)
        acc[mi][ni] = __builtin_amdgcn_mfma_f32_16x16x32_bf16(af[mi], bf[ni], acc[mi][ni], 0, 0, 0);
    __syncthreads();
  }

  float* outf = (float*)Cout;
  unsigned short* outb = (unsigned short*)Cout;
#pragma unroll
  for (int mi = 0; mi < 4; ++mi) {
#pragma unroll
    for (int ni = 0; ni < 4; ++ni) {
      const size_t row0 = bm + wrow + mi * 16 + quad * 4;
      const size_t col  = bn + wcol + ni * 16 + lr;
      const float bsum = bias ? bias[col] : 0.f;
#pragma unroll
      for (int reg = 0; reg < 4; ++reg) {
        const float v = acc[mi][ni][reg] + bsum;
        if (out_bf16) outb[(row0 + reg) * (size_t)N + col] = f2bf(v);
        else          outf[(row0 + reg) * (size_t)N + col] = v;
      }
    }
  }
}

// ---------------------------------------------------------------------------
// small helpers
// ---------------------------------------------------------------------------
// in[K,N] fp32 -> out[N,K] bf16 (tiled transpose). K%32==0, N%32==0.
__global__ __launch_bounds__(256) void transpose_f32_bf16(
    const float* __restrict__ in, unsigned short* __restrict__ outp, int K, int N) {
  __shared__ unsigned short tile[32][33];
  const int tid = threadIdx.x;
  const int tx = tid & 31, ty = tid >> 5;  // ty 0..7
  const int k0 = blockIdx.y * 32, n0 = blockIdx.x * 32;
#pragma unroll
  for (int i = 0; i < 4; ++i) {
    const int kk = ty + i * 8;
    tile[tx][kk] = f2bf(in[(size_t)(k0 + kk) * N + n0 + tx]);
  }
  __syncthreads();
#pragma unroll
  for (int i = 0; i < 4; ++i) {
    const int nn = ty + i * 8;
    outp[(size_t)(n0 + nn) * K + k0 + tx] = tile[nn][tx];
  }
}

// bcat[2048] = [att_hid_bias | rec_bias]
__global__ void build_bcat(const float* __restrict__ ahb,
                           const float* __restrict__ rb,
                           float* __restrict__ bcat) {
  int i = blockIdx.x * 256 + threadIdx.x;
  if (i < A_) bcat[i] = ahb[i];
  else if (i < A_ + N3U) bcat[i] = rb[i - A_];
}

// ---------------------------------------------------------------------------
// Persistent cooperative recurrence kernel. Grid = 256 blocks x 512 threads.
// Per step t:
//   phase 1 (batched MFMA): block j computes hm[m0:m0+128, n0:n0+16] where
//     n0=(j>>1)*16, m0=(j&1)*128; hm = h_bf16 @ Wcat^T + bcat. Weights/h are
//     L2-hot; each wave does 16 mfma_16x16x32 over K=512.
//   grid.sync()
//   phase 2 (per-b): block b computes attention scores + softmax -> aw in LDS.
//   phase 3 (per-b): combine mx = sum_l aw[l]*imgW[b,l,:] (+text_proj) via
//     ushort4 loads + LDS exchange; GRU gates; write h (fp32+bf16) and out.
//   grid.sync()
// ---------------------------------------------------------------------------
__global__ __launch_bounds__(512) void recurrence_coop(
    const unsigned short* __restrict__ img_proj,  // [B,L,A] bf16
    const unsigned short* __restrict__ imgW,      // [B,L,3U] bf16
    const float* __restrict__ text_proj,          // [B,T,3U] fp32
    const unsigned short* __restrict__ wcatT,     // [2048,512] bf16 ([ahk|rk]^T)
    const float* __restrict__ bcat,               // [2048]
    const float* __restrict__ vk,                 // [A]
    float* __restrict__ h,                        // [B,U] fp32
    unsigned short* __restrict__ hbf,             // [B,U] bf16
    float* __restrict__ hm,                       // [B,2048]
    float* __restrict__ out) {                    // [B,T,U]
  cg::grid_group grid = cg::this_grid();
  const int bid  = blockIdx.x;
  const int tid  = threadIdx.x;
  const int lane = tid & 63;
  const int wave = tid >> 6;   // 0..7
  const int quad = lane >> 4;
  const int lr   = lane & 15;

  __shared__ float sc[L_];
  __shared__ float aw[L_];
  __shared__ float mxs[N3U];

  // init h = 0 (512 threads x 256 blocks covers B*U exactly)
  h[bid * U_ + tid] = 0.f;
  hbf[bid * U_ + tid] = 0;
  grid.sync();

  // phase-1 slice for this block
  const int n0  = (bid >> 1) * 16;
  const int m0w = (bid & 1) * 128 + wave * 16;
  const float bsum = bcat[n0 + lr];

  // per-lane slice of att_v (a = lane*8 + j), loop-invariant
  float vvv[8];
  {
    float4 v0 = *(const float4*)(vk + lane * 8);
    float4 v1 = *(const float4*)(vk + lane * 8 + 4);
    vvv[0]=v0.x; vvv[1]=v0.y; vvv[2]=v0.z; vvv[3]=v0.w;
    vvv[4]=v1.x; vvv[5]=v1.y; vvv[6]=v1.z; vvv[7]=v1.w;
  }

  for (int t = 0; t < T_; ++t) {
    // ---- phase 1: hm = h @ Wcat + bcat (MFMA, batched over all b) ----
    {
      floatx4 acc = {0.f, 0.f, 0.f, 0.f};
      const unsigned short* ab = hbf + (size_t)(m0w + lr) * U_;
      const unsigned short* bb = wcatT + (size_t)(n0 + lr) * U_;
#pragma unroll
      for (int k0 = 0; k0 < U_; k0 += 32) {
        short8 afr = *(const short8*)(ab + k0 + quad * 8);
        short8 bfr = *(const short8*)(bb + k0 + quad * 8);
        acc = __builtin_amdgcn_mfma_f32_16x16x32_bf16(afr, bfr, acc, 0, 0, 0);
      }
#pragma unroll
      for (int r = 0; r < 4; ++r)
        hm[(size_t)(m0w + quad * 4 + r) * 2048 + n0 + lr] = acc[r] + bsum;
    }
    grid.sync();

    // ---- phase 2: attention scores + softmax for batch bid ----
    {
      const float* hp = hm + (size_t)bid * 2048;  // hproj = cols [0,512)
      float hpv[8];
      float4 h0 = *(const float4*)(hp + lane * 8);
      float4 h1 = *(const float4*)(hp + lane * 8 + 4);
      hpv[0]=h0.x; hpv[1]=h0.y; hpv[2]=h0.z; hpv[3]=h0.w;
      hpv[4]=h1.x; hpv[5]=h1.y; hpv[6]=h1.z; hpv[7]=h1.w;
#pragma unroll
      for (int i = 0; i < 8; ++i) {
        const int l = wave + i * 8;
        short8 v8 = *(const short8*)(img_proj + ((size_t)bid * L_ + l) * A_ + lane * 8);
        float s = 0.f;
#pragma unroll
        for (int j = 0; j < 8; ++j)
          s += fast_tanh(bf2f((unsigned short)v8[j]) + hpv[j]) * vvv[j];
#pragma unroll
        for (int off = 32; off; off >>= 1) s += __shfl_down(s, off);
        if (lane == 0) sc[l] = s;
      }
      __syncthreads();
      if (tid < 64) {
        float x = sc[tid];
        float m = x;
#pragma unroll
        for (int off = 32; off; off >>= 1) m = fmaxf(m, __shfl_xor(m, off));
        float e = __expf(x - m);
        float ssum = e;
#pragma unroll
        for (int off = 32; off; off >>= 1) ssum += __shfl_xor(ssum, off);
        aw[tid] = e / ssum;
      }
      __syncthreads();
    }

    // ---- phase 3: combine (vectorized) + GRU gates ----
    if (tid < 384) {
      const unsigned short* iwp = imgW + (size_t)bid * L_ * N3U + tid * 4;
      float a0 = 0.f, a1 = 0.f, a2 = 0.f, a3 = 0.f;
#pragma unroll 16
      for (int l = 0; l < L_; ++l) {
        const float a = aw[l];
        ushort4 w = *(const ushort4*)(iwp + (size_t)l * N3U);
        a0 += a * bf2f(w.x); a1 += a * bf2f(w.y);
        a2 += a * bf2f(w.z); a3 += a * bf2f(w.w);
      }
      float4 t4 = *(const float4*)(text_proj + ((size_t)bid * T_ + t) * N3U + tid * 4);
      mxs[tid * 4 + 0] = a0 + t4.x;
      mxs[tid * 4 + 1] = a1 + t4.y;
      mxs[tid * 4 + 2] = a2 + t4.z;
      mxs[tid * 4 + 3] = a3 + t4.w;
    }
    __syncthreads();
    {
      const int u = tid;
      const float* mib = hm + (size_t)bid * 2048 + 512;  // mi = cols [512,2048)
      const float xz = mxs[u]        + mib[u];
      const float xr = mxs[512 + u]  + mib[512 + u];
      const float xh = mxs[1024 + u];
      const float rh = mib[1024 + u];
      const float z = sigmoidf(xz);
      const float r = sigmoidf(xr);
      const float hh = fast_tanh(xh + r * rh);
      const float hn = z * h[bid * U_ + u] + (1.f - z) * hh;
      h[bid * U_ + u] = hn;
      hbf[bid * U_ + u] = f2bf(hn);
      out[((size_t)bid * T_ + t) * U_ + u] = hn;
    }
    grid.sync();
  }
}

// ---------------------------------------------------------------------------
// launch
// ---------------------------------------------------------------------------
extern "C" void kernel_launch(void* const* d_in, const int* in_sizes, int n_in,
                              void* d_out, int out_size, void* d_ws, size_t ws_size,
                              hipStream_t stream) {
  const float* img        = (const float*)d_in[0];   // [B,L,DI]
  const float* text       = (const float*)d_in[1];   // [B,T,DT]
  const float* kern       = (const float*)d_in[2];   // [DT+DI, 3U]
  const float* input_bias = (const float*)d_in[3];   // [3U]
  const float* rec_kern   = (const float*)d_in[4];   // [U,3U]
  const float* rec_bias   = (const float*)d_in[5];   // [3U]
  const float* att_img_k  = (const float*)d_in[6];   // [DI,A]
  const float* att_img_b  = (const float*)d_in[7];   // [A]
  const float* att_hid_k  = (const float*)d_in[8];   // [U,A]
  const float* att_hid_b  = (const float*)d_in[9];   // [A]
  const float* att_v_k    = (const float*)d_in[10];  // [A,1]
  // d_in[11] = att_v_bias — cancels in softmax.
  float* out = (float*)d_out;

  // workspace layout (bytes, 256-aligned). NO ALIASING. ~132 MB total.
  char* ws = (char*)d_ws;
  size_t off = 0;
  auto alloc = [&](size_t bytes) { char* p = ws + off; off += (bytes + 255) & ~(size_t)255; return p; };
  unsigned short* img_proj = (unsigned short*)alloc((size_t)B_*L_*A_*2);   // 16.8 MB bf16
  unsigned short* imgW     = (unsigned short*)alloc((size_t)B_*L_*N3U*2);  // 50.3 MB bf16
  float*          text_proj= (float*)         alloc((size_t)B_*T_*N3U*4);  // 50.3 MB fp32
  unsigned short* wt1      = (unsigned short*)alloc((size_t)A_*DI_*2);     // att_img_k^T
  unsigned short* wt2      = (unsigned short*)alloc((size_t)N3U*DI_*2);    // kern[DT:]^T
  unsigned short* wt3      = (unsigned short*)alloc((size_t)N3U*DT_*2);    // kern[:DT]^T
  unsigned short* wcatT    = (unsigned short*)alloc((size_t)2048*U_*2);    // [ahk|rk]^T bf16
  float*          bcat     = (float*)         alloc(2048*4);
  float*          h        = (float*)         alloc((size_t)B_*U_*4);
  unsigned short* hbf      = (unsigned short*)alloc((size_t)B_*U_*2);
  float*          hm       = (float*)         alloc((size_t)B_*2048*4);

  dim3 blk(256);

  // one-time weight transposes (fp32 -> bf16^T)
  transpose_f32_bf16<<<dim3(A_/32, DI_/32), blk, 0, stream>>>(att_img_k, wt1, DI_, A_);
  transpose_f32_bf16<<<dim3(N3U/32, DI_/32), blk, 0, stream>>>(kern + (size_t)DT_*N3U, wt2, DI_, N3U);
  transpose_f32_bf16<<<dim3(N3U/32, DT_/32), blk, 0, stream>>>(kern, wt3, DT_, N3U);
  transpose_f32_bf16<<<dim3(A_/32, U_/32), blk, 0, stream>>>(att_hid_k, wcatT, U_, A_);
  transpose_f32_bf16<<<dim3(N3U/32, U_/32), blk, 0, stream>>>(rec_kern, wcatT + (size_t)A_*U_, U_, N3U);
  build_bcat<<<dim3(8), blk, 0, stream>>>(att_hid_b, rec_bias, bcat);

  // big GEMMs on MFMA (A operand converted fp32->bf16 during staging)
  gemm_a32_bt16_mfma<<<dim3(A_/128, (B_*L_)/128), blk, 0, stream>>>(
      img, wt1, att_img_b, img_proj, B_*L_, A_, DI_, 1);
  gemm_a32_bt16_mfma<<<dim3(N3U/128, (B_*L_)/128), blk, 0, stream>>>(
      img, wt2, nullptr, imgW, B_*L_, N3U, DI_, 1);
  gemm_a32_bt16_mfma<<<dim3(N3U/128, (B_*T_)/128), blk, 0, stream>>>(
      text, wt3, input_bias, text_proj, B_*T_, N3U, DT_, 0);

  // whole recurrence in ONE cooperative launch (h init happens in-kernel)
  void* args[] = { (void*)&img_proj, (void*)&imgW, (void*)&text_proj,
                   (void*)&wcatT, (void*)&bcat, (void*)&att_v_k,
                   (void*)&h, (void*)&hbf, (void*)&hm, (void*)&out };
  hipLaunchCooperativeKernel((const void*)recurrence_coop,
                             dim3(B_), dim3(512), args, 0, stream);
}

// Round 6
// 3256.693 us; speedup vs baseline: 1.0663x; 1.0663x over previous
//
#include <hip/hip_runtime.h>
#include <hip/hip_bf16.h>

// Problem dims (fixed by reference)
#define B_  256
#define L_  64
#define DI_ 2048
#define T_  32
#define DT_ 512
#define U_  512
#define A_  512
#define N3U 1536   // 3*U

typedef short short8 __attribute__((ext_vector_type(8)));   // 8 bf16 = 4 VGPRs
typedef float floatx4 __attribute__((ext_vector_type(4)));  // mfma acc

// fp32 -> bf16 round-to-nearest-even
__device__ __forceinline__ unsigned short f2bf(float f) {
  unsigned int u = __float_as_uint(f);
  u += 0x7fffu + ((u >> 16) & 1u);
  return (unsigned short)(u >> 16);
}
__device__ __forceinline__ float bf2f(unsigned short s) {
  return __uint_as_float(((unsigned int)s) << 16);
}
__device__ __forceinline__ float fast_tanh(float x) {
  x = fminf(fmaxf(x, -15.f), 15.f);
  float e = __expf(2.f * x);
  return (e - 1.f) / (e + 1.f);
}
__device__ __forceinline__ float sigmoidf(float x) {
  return 1.f / (1.f + __expf(-x));
}

// ---------------------------------------------------------------------------
// MFMA GEMM with fused A-conversion (precompute only):
//   C[M,N] = A[M,K](fp32) @ Bt[N,K](bf16)^T (+bias), out fp32 or bf16.
// 128x128 tile, BK=32, 256 threads = 4 waves, each wave 64x64 sub-tile.
// ---------------------------------------------------------------------------
__global__ __launch_bounds__(256) void gemm_a32_bt16_mfma(
    const float* __restrict__ A, const unsigned short* __restrict__ Bt,
    const float* __restrict__ bias, void* __restrict__ Cout,
    int M, int N, int K, int out_bf16) {
  __shared__ unsigned short As[128][40];
  __shared__ unsigned short Bs[128][40];
  const int tid  = threadIdx.x;
  const int wave = tid >> 6;
  const int lane = tid & 63;
  const int quad = lane >> 4;
  const int lr   = lane & 15;
  const int wrow = (wave >> 1) * 64;
  const int wcol = (wave & 1) * 64;
  const size_t bm = (size_t)blockIdx.y * 128;
  const size_t bn = (size_t)blockIdx.x * 128;

  const int sr = tid >> 2;          // staging row 0..63
  const int sc = (tid & 3) * 8;     // staging col (ushorts) 0,8,16,24

  floatx4 acc[4][4] = {};

  for (int k0 = 0; k0 < K; k0 += 32) {
#pragma unroll
    for (int it = 0; it < 2; ++it) {
      const int row = sr + it * 64;
      const float* ap = A + (bm + row) * (size_t)K + k0 + sc;
      float4 a0 = *(const float4*)(ap);
      float4 a1 = *(const float4*)(ap + 4);
      short8 pk;
      pk[0] = (short)f2bf(a0.x); pk[1] = (short)f2bf(a0.y);
      pk[2] = (short)f2bf(a0.z); pk[3] = (short)f2bf(a0.w);
      pk[4] = (short)f2bf(a1.x); pk[5] = (short)f2bf(a1.y);
      pk[6] = (short)f2bf(a1.z); pk[7] = (short)f2bf(a1.w);
      *(short8*)&As[row][sc] = pk;
      *(float4*)&Bs[row][sc] = *(const float4*)(Bt + (bn + row) * (size_t)K + k0 + sc);
    }
    __syncthreads();
    short8 af[4], bf[4];
#pragma unroll
    for (int mi = 0; mi < 4; ++mi) af[mi] = *(const short8*)&As[wrow + mi * 16 + lr][quad * 8];
#pragma unroll
    for (int ni = 0; ni < 4; ++ni) bf[ni] = *(const short8*)&Bs[wcol + ni * 16 + lr][quad * 8];
#pragma unroll
    for (int mi = 0; mi < 4; ++mi)
#pragma unroll
      for (int ni = 0; ni < 4; ++ni)
        acc[mi][ni] = __builtin_amdgcn_mfma_f32_16x16x32_bf16(af[mi], bf[ni], acc[mi][ni], 0, 0, 0);
    __syncthreads();
  }

  float* outf = (float*)Cout;
  unsigned short* outb = (unsigned short*)Cout;
#pragma unroll
  for (int mi = 0; mi < 4; ++mi) {
#pragma unroll
    for (int ni = 0; ni < 4; ++ni) {
      const size_t row0 = bm + wrow + mi * 16 + quad * 4;
      const size_t col  = bn + wcol + ni * 16 + lr;
      const float bsum = bias ? bias[col] : 0.f;
#pragma unroll
      for (int reg = 0; reg < 4; ++reg) {
        const float v = acc[mi][ni][reg] + bsum;
        if (out_bf16) outb[(row0 + reg) * (size_t)N + col] = f2bf(v);
        else          outf[(row0 + reg) * (size_t)N + col] = v;
      }
    }
  }
}

// ---------------------------------------------------------------------------
// small helpers
// ---------------------------------------------------------------------------
// in[K,N] fp32 -> out[N,K] bf16 (tiled transpose). K%32==0, N%32==0.
__global__ __launch_bounds__(256) void transpose_f32_bf16(
    const float* __restrict__ in, unsigned short* __restrict__ outp, int K, int N) {
  __shared__ unsigned short tile[32][33];
  const int tid = threadIdx.x;
  const int tx = tid & 31, ty = tid >> 5;  // ty 0..7
  const int k0 = blockIdx.y * 32, n0 = blockIdx.x * 32;
#pragma unroll
  for (int i = 0; i < 4; ++i) {
    const int kk = ty + i * 8;
    tile[tx][kk] = f2bf(in[(size_t)(k0 + kk) * N + n0 + tx]);
  }
  __syncthreads();
#pragma unroll
  for (int i = 0; i < 4; ++i) {
    const int nn = ty + i * 8;
    outp[(size_t)(n0 + nn) * K + k0 + tx] = tile[nn][tx];
  }
}

// bcat[2048] = [att_hid_bias | rec_bias]
__global__ void build_bcat(const float* __restrict__ ahb,
                           const float* __restrict__ rb,
                           float* __restrict__ bcat) {
  int i = blockIdx.x * 256 + threadIdx.x;
  if (i < A_) bcat[i] = ahb[i];
  else if (i < A_ + N3U) bcat[i] = rb[i - A_];
}

// ---------------------------------------------------------------------------
// Block-local recurrence: 128 blocks x 512 threads; block bid owns batch
// elements b0=2*bid, b0+1 for ALL T=32 steps. h, hm, attw, mx live in LDS.
// NO cross-block communication -> no grid syncs, no launches, no XCD
// coherence traffic. Per step:
//   phase 1: hm[2][2048] = h @ [ahk|rk] + bcat via MFMA (M padded 2->16 with
//            zero rows in h_pad). Weights (2 MB bf16) streamed from L2.
//   phase 2: scores + softmax (waves 0-3: b=0, waves 4-7: b=1).
//   phase 3: mx = sum_l aw[l]*imgW[b,l,:] + text_proj (ushort4 vectorized).
//   gates:   z/r/hh + h update (LDS) + out store (global, coalesced).
// ---------------------------------------------------------------------------
__global__ __launch_bounds__(512) void recurrence_block(
    const unsigned short* __restrict__ img_proj,  // [B,L,A] bf16
    const unsigned short* __restrict__ imgW,      // [B,L,3U] bf16
    const float* __restrict__ text_proj,          // [B,T,3U] fp32
    const unsigned short* __restrict__ wcatT,     // [2048,512] bf16 ([ahk|rk]^T)
    const float* __restrict__ bcat,               // [2048]
    const float* __restrict__ vk,                 // [A]
    float* __restrict__ out) {                    // [B,T,U]
  const int bid  = blockIdx.x;
  const int b0   = bid * 2;
  const int tid  = threadIdx.x;
  const int lane = tid & 63;
  const int wave = tid >> 6;   // 0..7
  const int quad = lane >> 4;
  const int lr   = lane & 15;

  // LDS (~49 KB): all recurrent state is block-private.
  __shared__ unsigned short h_pad[16][520];  // bf16 h, M padded to 16 (rows 2..15 = 0); +8 pad vs bank conflicts
  __shared__ float h_f[2][512];              // fp32 h for the z*h term
  __shared__ float hm_s[2][2048];            // [hproj | mi] per b
  __shared__ float sc_s[2][64];
  __shared__ float aw_s[2][64];
  __shared__ float mx_s[2][N3U];

  // init LDS state
  for (int i = tid; i < 16 * 520; i += 512) ((unsigned short*)h_pad)[i] = 0;
  for (int i = tid; i < 2 * 512; i += 512) ((float*)h_f)[i] = 0.f;
  __syncthreads();

  // loop-invariant: per-lane slice of att_v (a = lane*8 + j)
  float vvv[8];
  {
    float4 v0 = *(const float4*)(vk + lane * 8);
    float4 v1 = *(const float4*)(vk + lane * 8 + 4);
    vvv[0]=v0.x; vvv[1]=v0.y; vvv[2]=v0.z; vvv[3]=v0.w;
    vvv[4]=v1.x; vvv[5]=v1.y; vvv[6]=v1.z; vvv[7]=v1.w;
  }

  for (int t = 0; t < T_; ++t) {
    // ---- phase 1: hm = h @ Wcat + bcat (MFMA, M=16 padded) ----
    {
      // hoist the 16 A-fragments (whole K=512 of h) into registers
      short8 af[16];
#pragma unroll
      for (int kk = 0; kk < 16; ++kk)
        af[kk] = *(const short8*)&h_pad[lr][kk * 32 + quad * 8];
      const int ntbase = wave * 16;   // wave owns 16 N-tiles of 16 cols
#pragma unroll 4
      for (int ntl = 0; ntl < 16; ++ntl) {
        const int n0 = (ntbase + ntl) * 16;
        const unsigned short* bp = wcatT + (size_t)(n0 + lr) * U_ + quad * 8;
        floatx4 acc = {0.f, 0.f, 0.f, 0.f};
#pragma unroll
        for (int kk = 0; kk < 16; ++kk) {
          short8 bfr = *(const short8*)(bp + kk * 32);
          acc = __builtin_amdgcn_mfma_f32_16x16x32_bf16(af[kk], bfr, acc, 0, 0, 0);
        }
        if (quad == 0) {   // rows 0,1 of C live in quad 0, regs 0,1
          const float bb = bcat[n0 + lr];
          hm_s[0][n0 + lr] = acc[0] + bb;
          hm_s[1][n0 + lr] = acc[1] + bb;
        }
      }
    }
    __syncthreads();

    // ---- phase 2: attention scores (waves 0-3: b=0; 4-7: b=1) ----
    {
      const int b2 = wave >> 2;
      const int wl = wave & 3;
      float hpv[8];
#pragma unroll
      for (int j = 0; j < 8; ++j) hpv[j] = hm_s[b2][lane * 8 + j];
#pragma unroll 4
      for (int i = 0; i < 16; ++i) {
        const int l = wl * 16 + i;
        short8 v8 = *(const short8*)(img_proj + ((size_t)(b0 + b2) * L_ + l) * A_ + lane * 8);
        float s = 0.f;
#pragma unroll
        for (int j = 0; j < 8; ++j)
          s += fast_tanh(bf2f((unsigned short)v8[j]) + hpv[j]) * vvv[j];
#pragma unroll
        for (int off = 32; off; off >>= 1) s += __shfl_down(s, off);
        if (lane == 0) sc_s[b2][l] = s;
      }
    }
    __syncthreads();

    // softmax over L=64, both b's in parallel (waves 0 and 1)
    if (tid < 128) {
      const int b2 = tid >> 6;
      const int l  = tid & 63;
      float x = sc_s[b2][l];
      float m = x;
#pragma unroll
      for (int off = 32; off; off >>= 1) m = fmaxf(m, __shfl_xor(m, off));
      float e = __expf(x - m);
      float ssum = e;
#pragma unroll
      for (int off = 32; off; off >>= 1) ssum += __shfl_xor(ssum, off);
      aw_s[b2][l] = e / ssum;
    }
    __syncthreads();

    // ---- phase 3: combine mx = sum_l aw[l]*imgW + text_proj ----
    for (int task = tid; task < 768; task += 512) {
      const int b2 = (task >= 384) ? 1 : 0;
      const int c4 = task - b2 * 384;
      const unsigned short* iwp = imgW + (size_t)(b0 + b2) * L_ * N3U + c4 * 4;
      const float* awp = aw_s[b2];
      float a0 = 0.f, a1 = 0.f, a2 = 0.f, a3 = 0.f;
#pragma unroll 8
      for (int l = 0; l < L_; ++l) {
        const float a = awp[l];
        ushort4 w = *(const ushort4*)(iwp + (size_t)l * N3U);
        a0 += a * bf2f(w.x); a1 += a * bf2f(w.y);
        a2 += a * bf2f(w.z); a3 += a * bf2f(w.w);
      }
      float4 t4 = *(const float4*)(text_proj + ((size_t)(b0 + b2) * T_ + t) * N3U + c4 * 4);
      mx_s[b2][c4 * 4 + 0] = a0 + t4.x;
      mx_s[b2][c4 * 4 + 1] = a1 + t4.y;
      mx_s[b2][c4 * 4 + 2] = a2 + t4.z;
      mx_s[b2][c4 * 4 + 3] = a3 + t4.w;
    }
    __syncthreads();

    // ---- gates: 1024 (b,u) tasks over 512 threads ----
    for (int task = tid; task < 1024; task += 512) {
      const int b2 = task >> 9;
      const int u  = task & 511;
      const float* mib = &hm_s[b2][512];
      const float xz = mx_s[b2][u]        + mib[u];
      const float xr = mx_s[b2][512 + u]  + mib[512 + u];
      const float xh = mx_s[b2][1024 + u];
      const float rh = mib[1024 + u];
      const float z  = sigmoidf(xz);
      const float r  = sigmoidf(xr);
      const float hh = fast_tanh(xh + r * rh);
      const float hn = z * h_f[b2][u] + (1.f - z) * hh;
      h_f[b2][u] = hn;
      h_pad[b2][u] = f2bf(hn);
      out[((size_t)(b0 + b2) * T_ + t) * U_ + u] = hn;
    }
    __syncthreads();
  }
}

// ---------------------------------------------------------------------------
// launch
// ---------------------------------------------------------------------------
extern "C" void kernel_launch(void* const* d_in, const int* in_sizes, int n_in,
                              void* d_out, int out_size, void* d_ws, size_t ws_size,
                              hipStream_t stream) {
  const float* img        = (const float*)d_in[0];   // [B,L,DI]
  const float* text       = (const float*)d_in[1];   // [B,T,DT]
  const float* kern       = (const float*)d_in[2];   // [DT+DI, 3U]
  const float* input_bias = (const float*)d_in[3];   // [3U]
  const float* rec_kern   = (const float*)d_in[4];   // [U,3U]
  const float* rec_bias   = (const float*)d_in[5];   // [3U]
  const float* att_img_k  = (const float*)d_in[6];   // [DI,A]
  const float* att_img_b  = (const float*)d_in[7];   // [A]
  const float* att_hid_k  = (const float*)d_in[8];   // [U,A]
  const float* att_hid_b  = (const float*)d_in[9];   // [A]
  const float* att_v_k    = (const float*)d_in[10];  // [A,1]
  // d_in[11] = att_v_bias — cancels in softmax.
  float* out = (float*)d_out;

  // workspace layout (bytes, 256-aligned). NO ALIASING. ~130 MB total.
  char* ws = (char*)d_ws;
  size_t off = 0;
  auto alloc = [&](size_t bytes) { char* p = ws + off; off += (bytes + 255) & ~(size_t)255; return p; };
  unsigned short* img_proj = (unsigned short*)alloc((size_t)B_*L_*A_*2);   // 16.8 MB bf16
  unsigned short* imgW     = (unsigned short*)alloc((size_t)B_*L_*N3U*2);  // 50.3 MB bf16
  float*          text_proj= (float*)         alloc((size_t)B_*T_*N3U*4);  // 50.3 MB fp32
  unsigned short* wt1      = (unsigned short*)alloc((size_t)A_*DI_*2);     // att_img_k^T
  unsigned short* wt2      = (unsigned short*)alloc((size_t)N3U*DI_*2);    // kern[DT:]^T
  unsigned short* wt3      = (unsigned short*)alloc((size_t)N3U*DT_*2);    // kern[:DT]^T
  unsigned short* wcatT    = (unsigned short*)alloc((size_t)2048*U_*2);    // [ahk|rk]^T bf16
  float*          bcat     = (float*)         alloc(2048*4);

  dim3 blk(256);

  // one-time weight transposes (fp32 -> bf16^T)
  transpose_f32_bf16<<<dim3(A_/32, DI_/32), blk, 0, stream>>>(att_img_k, wt1, DI_, A_);
  transpose_f32_bf16<<<dim3(N3U/32, DI_/32), blk, 0, stream>>>(kern + (size_t)DT_*N3U, wt2, DI_, N3U);
  transpose_f32_bf16<<<dim3(N3U/32, DT_/32), blk, 0, stream>>>(kern, wt3, DT_, N3U);
  transpose_f32_bf16<<<dim3(A_/32, U_/32), blk, 0, stream>>>(att_hid_k, wcatT, U_, A_);
  transpose_f32_bf16<<<dim3(N3U/32, U_/32), blk, 0, stream>>>(rec_kern, wcatT + (size_t)A_*U_, U_, N3U);
  build_bcat<<<dim3(8), blk, 0, stream>>>(att_hid_b, rec_bias, bcat);

  // big GEMMs on MFMA (A operand converted fp32->bf16 during staging)
  gemm_a32_bt16_mfma<<<dim3(A_/128, (B_*L_)/128), blk, 0, stream>>>(
      img, wt1, att_img_b, img_proj, B_*L_, A_, DI_, 1);
  gemm_a32_bt16_mfma<<<dim3(N3U/128, (B_*L_)/128), blk, 0, stream>>>(
      img, wt2, nullptr, imgW, B_*L_, N3U, DI_, 1);
  gemm_a32_bt16_mfma<<<dim3(N3U/128, (B_*T_)/128), blk, 0, stream>>>(
      text, wt3, input_bias, text_proj, B_*T_, N3U, DT_, 0);

  // whole recurrence: ONE plain launch, zero cross-block communication
  recurrence_block<<<dim3(128), dim3(512), 0, stream>>>(
      img_proj, imgW, text_proj, wcatT, bcat, att_v_k, out);
}